// Round 10
// baseline (342.071 us; speedup 1.0000x reference)
//
#include <hip/hip_runtime.h>
#include <math.h>

namespace {

constexpr int B_ = 4;
constexpr int N_ = 512;
constexpr int D_ = 256;
constexpr int L_ = 128;
constexpr int TI = 8;    // i-rows per dist block
constexpr int REP_P = 24;  // proj instrumentation multiplier
constexpr int REP_D = 16;  // dist instrumentation multiplier

// xs[b][l][n] = a[l] * sum_d x[b][n][d] * W[l][d]
// R8 structure, XCD-pinned; {x-stage + compute} wrapped in REP_P for rocprof.
__global__ __launch_bounds__(256) void proj_kernel(
    const float* __restrict__ x, const float* __restrict__ W,
    const float* __restrict__ a, float* __restrict__ xs) {
  const int bid = blockIdx.x;       // 0..255
  const int xcd = bid & 7;          // round-robin XCD assignment
  const int b = xcd >> 1;           // batch pinned to XCD pair
  const int tile = ((xcd & 1) << 5) + (bid >> 3);  // 0..63
  const int l0 = (tile >> 3) * 16;
  const int n0 = (tile & 7) * 64;

  const int t = threadIdx.x;

  __shared__ float wl_s[16 * 256];  // 16 KB W tile
  __shared__ float xl[64 * 129];    // 33 KB x half-tile, pad 129

  const int n = t & 63;
  const int lg = t >> 6;  // 0..3, wave-uniform
  const float* __restrict__ xrow = xl + n * 129;

  // stage W tile (16 l x 256 d), coalesced float4 (outside REP)
  {
    const float4* __restrict__ Wsrc =
        reinterpret_cast<const float4*>(W + (size_t)l0 * D_);
    float4* wdst = reinterpret_cast<float4*>(wl_s);
#pragma unroll
    for (int k = 0; k < 4; ++k) wdst[t + k * 256] = Wsrc[t + k * 256];
  }

  float acc[4];
  for (int rep = 0; rep < REP_P; ++rep) {
#pragma unroll
    for (int k = 0; k < 4; ++k) acc[k] = 0.f;
#pragma unroll
    for (int half = 0; half < 2; ++half) {
      __syncthreads();  // W ready / protect x reuse
      {
        const float4* __restrict__ xsrc = reinterpret_cast<const float4*>(
            x + ((size_t)(b * N_ + n0)) * D_ + half * 128);
#pragma unroll
        for (int k = 0; k < 8; ++k) {
          const int idx = t + k * 256;  // 0..2047
          const int sn = idx >> 5;      // local n
          const int sq = idx & 31;      // float4 within 128-chunk
          const float4 v = xsrc[(size_t)sn * 64 + sq];
          float* dst = xl + sn * 129 + sq * 4;
          dst[0] = v.x; dst[1] = v.y; dst[2] = v.z; dst[3] = v.w;
        }
      }
      __syncthreads();

      const float4* __restrict__ w4 = reinterpret_cast<const float4*>(wl_s);
#pragma unroll 4
      for (int d4 = 0; d4 < 32; ++d4) {
        const float x0 = xrow[d4 * 4 + 0];
        const float x1 = xrow[d4 * 4 + 1];
        const float x2 = xrow[d4 * 4 + 2];
        const float x3 = xrow[d4 * 4 + 3];
#pragma unroll
        for (int k = 0; k < 4; ++k) {
          const float4 w = w4[(lg * 4 + k) * 64 + half * 32 + d4];
          acc[k] += x0 * w.x + x1 * w.y + x2 * w.z + x3 * w.w;
        }
      }
    }
    asm volatile("" ::"v"(acc[0]), "v"(acc[1]), "v"(acc[2]), "v"(acc[3]));
  }

#pragma unroll
  for (int k = 0; k < 4; ++k) {
    const int l = l0 + lg * 4 + k;
    xs[((size_t)(b * L_ + l)) * N_ + n0 + n] = acc[k] * a[l];  // coalesced
  }
}

// dist+softmax: TI=8, 16-deep xj prefetch, XCD-pinned; main loop x REP_D.
__global__ __launch_bounds__(512) void dist_softmax_kernel(
    const float* __restrict__ xs, const float* __restrict__ adj,
    const int* __restrict__ box_num, const float* __restrict__ a,
    float* __restrict__ out) {
  const int bid = blockIdx.x;       // 0..255
  const int xcd = bid & 7;
  const int b = xcd >> 1;
  const int tile = ((xcd & 1) << 5) + (bid >> 3);  // 0..63
  const int i0 = tile * TI;

  const int t = threadIdx.x;
  const int j = t;
  const int bn = box_num[b];
  const float* __restrict__ xs_b = xs + (size_t)b * L_ * N_;

  __shared__ float xi_l[L_ * TI];  // [l][r], 4 KB, broadcast float4 reads
  __shared__ float red[8][TI];
  __shared__ float sa_l[2];
  __shared__ float rmax_s[TI];
  __shared__ float rsinv_s[TI];

  // stage i-rows: 1024 elems, 2/thread: (l = idx>>3, r = idx&7)
#pragma unroll
  for (int s = 0; s < 2; ++s) {
    const int idx = t + s * 512;
    xi_l[idx] = xs_b[(idx >> 3) * N_ + i0 + (idx & 7)];
  }

  // sum(a) prologue
  {
    float sa = (t < L_) ? a[t] : 0.f;
#pragma unroll
    for (int off = 1; off < 64; off <<= 1) sa += __shfl_xor(sa, off);
    if (t == 0) sa_l[0] = sa;
    if (t == 64) sa_l[1] = sa;
  }
  __syncthreads();
  const float sum_a = sa_l[0] + sa_l[1];

  float acc[TI];
  const float4* __restrict__ xi4 = reinterpret_cast<const float4*>(xi_l);

  for (int rep = 0; rep < REP_D; ++rep) {
#pragma unroll
    for (int r = 0; r < TI; ++r) acc[r] = 0.f;
#pragma unroll
    for (int c = 0; c < 8; ++c) {  // 8 chunks x 16 l
      float xj[16];
#pragma unroll
      for (int u = 0; u < 16; ++u) {
        xj[u] = xs_b[(c * 16 + u) * N_ + j];  // batched issue, then waits
      }
#pragma unroll
      for (int u = 0; u < 16; ++u) {
        const float4 A = xi4[(c * 16 + u) * 2];      // broadcast b128
        const float4 Bv = xi4[(c * 16 + u) * 2 + 1];
        acc[0] += fabsf(A.x - xj[u]);
        acc[1] += fabsf(A.y - xj[u]);
        acc[2] += fabsf(A.z - xj[u]);
        acc[3] += fabsf(A.w - xj[u]);
        acc[4] += fabsf(Bv.x - xj[u]);
        acc[5] += fabsf(Bv.y - xj[u]);
        acc[6] += fabsf(Bv.z - xj[u]);
        acc[7] += fabsf(Bv.w - xj[u]);
      }
    }
    asm volatile("" ::"v"(acc[0]), "v"(acc[1]), "v"(acc[2]), "v"(acc[3]),
                 "v"(acc[4]), "v"(acc[5]), "v"(acc[6]), "v"(acc[7]));
  }

  const bool vj = j < bn;
  float val[TI];
#pragma unroll
  for (int r = 0; r < TI; ++r) {
    const bool vi = (i0 + r) < bn;
    const float d = acc[r] - ((vi && vj) ? 0.f : sum_a);  // + mask*sum(a)
    val[r] = d >= 0.f ? d : 0.01f * d;                    // leaky_relu
  }

  const int lane = t & 63;
  const int wid = t >> 6;

  // ---- row max over 512 j ----
  {
    float wm[TI];
#pragma unroll
    for (int r = 0; r < TI; ++r) {
      float m = val[r];
#pragma unroll
      for (int off = 1; off < 64; off <<= 1) m = fmaxf(m, __shfl_xor(m, off));
      wm[r] = m;
    }
    if (lane == 0) {
#pragma unroll
      for (int r = 0; r < TI; ++r) red[wid][r] = wm[r];
    }
  }
  __syncthreads();
  if (t < TI) {
    float m = red[0][t];
#pragma unroll
    for (int w = 1; w < 8; ++w) m = fmaxf(m, red[w][t]);
    rmax_s[t] = m;
  }
  __syncthreads();

  float e[TI];
  const float* __restrict__ adjp = adj + ((size_t)(b * N_ + i0)) * N_ + j;
#pragma unroll
  for (int r = 0; r < TI; ++r) {
    e[r] = adjp[(size_t)r * N_] * __expf(val[r] - rmax_s[r]);
  }

  // ---- row sum over 512 j ----
  {
    float wsum[TI];
#pragma unroll
    for (int r = 0; r < TI; ++r) {
      float s = e[r];
#pragma unroll
      for (int off = 1; off < 64; off <<= 1) s += __shfl_xor(s, off);
      wsum[r] = s;
    }
    if (lane == 0) {
#pragma unroll
      for (int r = 0; r < TI; ++r) red[wid][r] = wsum[r];
    }
  }
  __syncthreads();
  if (t < TI) {
    float s = red[0][t];
#pragma unroll
    for (int w = 1; w < 8; ++w) s += red[w][t];
    rsinv_s[t] = 1.0f / s;
  }
  __syncthreads();

  float* __restrict__ op = out + ((size_t)(b * N_ + i0)) * N_ + j;
#pragma unroll
  for (int r = 0; r < TI; ++r) {
    op[(size_t)r * N_] = e[r] * rsinv_s[r] + 1e-10f;
  }
}

}  // namespace

extern "C" void kernel_launch(void* const* d_in, const int* in_sizes, int n_in,
                              void* d_out, int out_size, void* d_ws,
                              size_t ws_size, hipStream_t stream) {
  const float* x = (const float*)d_in[0];    // (B,N,D) f32
  const float* adj = (const float*)d_in[1];  // (B,N,N) f32
  const int* box_num = (const int*)d_in[2];  // (B,1) int32
  const float* W = (const float*)d_in[3];    // (L,D) f32
  const float* a = (const float*)d_in[4];    // (L,) f32
  float* out = (float*)d_out;                // (B,N,N) f32
  float* xs = (float*)d_ws;                  // B*L*N floats = 1 MB scratch

  proj_kernel<<<256, 256, 0, stream>>>(x, W, a, xs);
  dist_softmax_kernel<<<256, 512, 0, stream>>>(xs, adj, box_num, a, out);
}

// Round 12
// 24.903 us; speedup vs baseline: 13.7363x; 13.7363x over previous
//
#include <hip/hip_runtime.h>
#include <hip/hip_fp16.h>
#include <math.h>

namespace {

constexpr int B_ = 4;
constexpr int N_ = 512;
constexpr int D_ = 256;
constexpr int L_ = 128;
constexpr int L2_ = L_ / 2;  // 64 packed l-pairs
constexpr int TI = 4;        // i-rows per dist block

typedef _Float16 v2h __attribute__((ext_vector_type(2)));

// xs_h2[b][l2][n] = f16x2( a[2l2]*dot(x[b][n],W[2l2]), a[2l2+1]*dot(...) )
// R8 proj structure (XCD-pinned, LDS-staged x and W); epilogue packs f16x2.
__global__ __launch_bounds__(256) void proj_kernel(
    const float* __restrict__ x, const float* __restrict__ W,
    const float* __restrict__ a, unsigned* __restrict__ xs_u) {
  const int bid = blockIdx.x;       // 0..255
  const int xcd = bid & 7;          // round-robin XCD assignment
  const int b = xcd >> 1;           // batch pinned to XCD pair
  const int tile = ((xcd & 1) << 5) + (bid >> 3);  // 0..63
  const int l0 = (tile >> 3) * 16;
  const int n0 = (tile & 7) * 64;

  const int t = threadIdx.x;

  __shared__ float wl_s[16 * 256];  // 16 KB W tile
  __shared__ float xl[64 * 129];    // 33 KB x half-tile, pad 129

  const int n = t & 63;
  const int lg = t >> 6;  // 0..3, wave-uniform
  const float* __restrict__ xrow = xl + n * 129;

  // stage W tile (16 l x 256 d), coalesced float4
  {
    const float4* __restrict__ Wsrc =
        reinterpret_cast<const float4*>(W + (size_t)l0 * D_);
    float4* wdst = reinterpret_cast<float4*>(wl_s);
#pragma unroll
    for (int k = 0; k < 4; ++k) wdst[t + k * 256] = Wsrc[t + k * 256];
  }

  float acc[4] = {0.f, 0.f, 0.f, 0.f};

#pragma unroll
  for (int half = 0; half < 2; ++half) {
    __syncthreads();  // W ready (half 0) / protect x reuse (half 1)
    {
      const float4* __restrict__ xsrc = reinterpret_cast<const float4*>(
          x + ((size_t)(b * N_ + n0)) * D_ + half * 128);
#pragma unroll
      for (int k = 0; k < 8; ++k) {
        const int idx = t + k * 256;  // 0..2047
        const int sn = idx >> 5;      // local n
        const int sq = idx & 31;      // float4 within 128-chunk
        const float4 v = xsrc[(size_t)sn * 64 + sq];
        float* dst = xl + sn * 129 + sq * 4;
        dst[0] = v.x; dst[1] = v.y; dst[2] = v.z; dst[3] = v.w;
      }
    }
    __syncthreads();

    const float4* __restrict__ w4 = reinterpret_cast<const float4*>(wl_s);
#pragma unroll 4
    for (int d4 = 0; d4 < 32; ++d4) {
      const float x0 = xrow[d4 * 4 + 0];
      const float x1 = xrow[d4 * 4 + 1];
      const float x2 = xrow[d4 * 4 + 2];
      const float x3 = xrow[d4 * 4 + 3];
#pragma unroll
      for (int k = 0; k < 4; ++k) {
        const float4 w = w4[(lg * 4 + k) * 64 + half * 32 + d4];  // broadcast
        acc[k] += x0 * w.x + x1 * w.y + x2 * w.z + x3 * w.w;
      }
    }
  }

  const int lbase = l0 + lg * 4;
  const float s0 = acc[0] * a[lbase + 0];
  const float s1 = acc[1] * a[lbase + 1];
  const float s2 = acc[2] * a[lbase + 2];
  const float s3 = acc[3] * a[lbase + 3];
  const auto p01 = __builtin_amdgcn_cvt_pkrtz(s0, s1);  // __fp16x2
  const auto p23 = __builtin_amdgcn_cvt_pkrtz(s2, s3);
  const int l2b = lbase >> 1;
  unsigned* o = xs_u + ((size_t)b * L2_ + l2b) * N_ + n0 + n;
  o[0] = __builtin_bit_cast(unsigned, p01);           // coalesced
  o[(size_t)N_] = __builtin_bit_cast(unsigned, p23);  // coalesced
}

// Fused dist+softmax, XCD-pinned (R8 mapping), TI=4, f16x2 math:
// per l-pair: pk_sub + packed-abs(and) + v_dot2_f32_f16 -> 3 VALU / 2 elems.
__global__ __launch_bounds__(512, 4) void dist_softmax_kernel(
    const unsigned* __restrict__ xs_u, const float* __restrict__ adj,
    const int* __restrict__ box_num, const float* __restrict__ a,
    float* __restrict__ out) {
  const int bid = blockIdx.x;       // 0..511
  const int xcd = bid & 7;
  const int b = xcd >> 1;
  const int tile = ((xcd & 1) << 6) + (bid >> 3);  // 0..127
  const int i0 = tile * TI;

  const int t = threadIdx.x;
  const int j = t;
  const int bn = box_num[b];
  const unsigned* __restrict__ xs_b = xs_u + (size_t)b * L2_ * N_;

  __shared__ unsigned xi_s[L2_ * TI];  // [l2][r] f16x2, 1 KB, b128 broadcast
  __shared__ float red[8][TI];
  __shared__ float sa_l[2];
  __shared__ float rmax_s[TI];
  __shared__ float rsinv_s[TI];

  // stage xi pairs: 256 u32, threads t<256: (l2 = t>>2, r = t&3)
  if (t < L2_ * TI) {
    xi_s[t] = xs_b[(t >> 2) * N_ + i0 + (t & 3)];
  }

  // sum(a) prologue (f32, exact)
  {
    float sa = (t < L_) ? a[t] : 0.f;
#pragma unroll
    for (int off = 1; off < 64; off <<= 1) sa += __shfl_xor(sa, off);
    if (t == 0) sa_l[0] = sa;
    if (t == 64) sa_l[1] = sa;
  }
  __syncthreads();
  const float sum_a = sa_l[0] + sa_l[1];

  float acc[TI];
#pragma unroll
  for (int r = 0; r < TI; ++r) acc[r] = 0.f;

  const v2h one2 = {(_Float16)1.0f, (_Float16)1.0f};
  const uint4* __restrict__ xi4 = reinterpret_cast<const uint4*>(xi_s);

#pragma unroll
  for (int c = 0; c < 8; ++c) {  // 8 chunks x 8 l-pairs
    unsigned xj[8];
#pragma unroll
    for (int u = 0; u < 8; ++u) {
      xj[u] = xs_b[(c * 8 + u) * N_ + j];  // coalesced b32, batched issue
    }
#pragma unroll
    for (int u = 0; u < 8; ++u) {
      const uint4 xi = xi4[c * 8 + u];  // broadcast ds_read_b128
      const unsigned xjw = xj[u];
      const unsigned xiw[4] = {xi.x, xi.y, xi.z, xi.w};
#pragma unroll
      for (int r = 0; r < TI; ++r) {
        const v2h d = __builtin_bit_cast(v2h, xiw[r]) -
                      __builtin_bit_cast(v2h, xjw);  // v_pk_sub_f16
        const unsigned du = __builtin_bit_cast(unsigned, d) & 0x7FFF7FFFu;
        acc[r] = __builtin_amdgcn_fdot2(__builtin_bit_cast(v2h, du), one2,
                                        acc[r], false);
      }
    }
  }

  const bool vj = j < bn;
  float val[TI];
#pragma unroll
  for (int r = 0; r < TI; ++r) {
    const bool vi = (i0 + r) < bn;
    const float d = acc[r] - ((vi && vj) ? 0.f : sum_a);  // + mask*sum(a)
    val[r] = d >= 0.f ? d : 0.01f * d;                    // leaky_relu
  }

  const int lane = t & 63;
  const int wid = t >> 6;

  // ---- row max over 512 j ----
  {
    float wm[TI];
#pragma unroll
    for (int r = 0; r < TI; ++r) {
      float m = val[r];
#pragma unroll
      for (int off = 1; off < 64; off <<= 1) m = fmaxf(m, __shfl_xor(m, off));
      wm[r] = m;
    }
    if (lane == 0) {
#pragma unroll
      for (int r = 0; r < TI; ++r) red[wid][r] = wm[r];
    }
  }
  __syncthreads();
  if (t < TI) {
    float m = red[0][t];
#pragma unroll
    for (int w = 1; w < 8; ++w) m = fmaxf(m, red[w][t]);
    rmax_s[t] = m;
  }
  __syncthreads();

  float e[TI];
  const float* __restrict__ adjp = adj + ((size_t)(b * N_ + i0)) * N_ + j;
#pragma unroll
  for (int r = 0; r < TI; ++r) {
    e[r] = adjp[(size_t)r * N_] * __expf(val[r] - rmax_s[r]);
  }

  // ---- row sum over 512 j ----
  {
    float wsum[TI];
#pragma unroll
    for (int r = 0; r < TI; ++r) {
      float s = e[r];
#pragma unroll
      for (int off = 1; off < 64; off <<= 1) s += __shfl_xor(s, off);
      wsum[r] = s;
    }
    if (lane == 0) {
#pragma unroll
      for (int r = 0; r < TI; ++r) red[wid][r] = wsum[r];
    }
  }
  __syncthreads();
  if (t < TI) {
    float s = red[0][t];
#pragma unroll
    for (int w = 1; w < 8; ++w) s += red[w][t];
    rsinv_s[t] = 1.0f / s;
  }
  __syncthreads();

  float* __restrict__ op = out + ((size_t)(b * N_ + i0)) * N_ + j;
#pragma unroll
  for (int r = 0; r < TI; ++r) {
    op[(size_t)r * N_] = e[r] * rsinv_s[r] + 1e-10f;
  }
}

}  // namespace

extern "C" void kernel_launch(void* const* d_in, const int* in_sizes, int n_in,
                              void* d_out, int out_size, void* d_ws,
                              size_t ws_size, hipStream_t stream) {
  const float* x = (const float*)d_in[0];    // (B,N,D) f32
  const float* adj = (const float*)d_in[1];  // (B,N,N) f32
  const int* box_num = (const int*)d_in[2];  // (B,1) int32
  const float* W = (const float*)d_in[3];    // (L,D) f32
  const float* a = (const float*)d_in[4];    // (L,) f32
  float* out = (float*)d_out;                // (B,N,N) f32
  unsigned* xs_u = (unsigned*)d_ws;          // B*64*512 u32 = 512 KB scratch

  proj_kernel<<<256, 256, 0, stream>>>(x, W, a, xs_u);
  dist_softmax_kernel<<<512, 512, 0, stream>>>(xs_u, adj, box_num, a, out);
}